// Round 1
// baseline (258.960 us; speedup 1.0000x reference)
//
#include <hip/hip_runtime.h>
#include <math.h>

#define NC 19
#define NB 8
#define HW (512 * 512)
#define CHUNKS 8
#define TPB 256

// Workspace layout: S[NB*NC*NC] floats, then counts[NB*NC] ints.

__global__ __launch_bounds__(TPB) void accum_kernel(const float* __restrict__ seg,
                                                    const int* __restrict__ tgt,
                                                    float* __restrict__ S,
                                                    int* __restrict__ counts) {
    // Per-thread private bins in LDS. Stride NC=19: gcd(19,32)=1 -> across a
    // wave64, lanes land on all 32 banks (2 lanes/bank = free on CDNA4).
    __shared__ float bins[TPB * NC];
    __shared__ int cbins[TPB * NC];

    const int tid = threadIdx.x;
    const int chunk = blockIdx.x;  // pixel chunk
    const int ci = blockIdx.y;     // channel i
    const int b = blockIdx.z;      // batch

    const bool do_count = (ci == 0);

    #pragma unroll
    for (int k = 0; k < NC; ++k) bins[tid * NC + k] = 0.0f;
    if (do_count) {
        #pragma unroll
        for (int k = 0; k < NC; ++k) cbins[tid * NC + k] = 0;
    }
    __syncthreads();

    const int per_chunk = HW / CHUNKS;  // 32768 pixels
    const int base = chunk * per_chunk;
    const float4* __restrict__ segv =
        (const float4*)(seg + ((size_t)(b * NC + ci)) * HW + base);
    const int4* __restrict__ tgtv = (const int4*)(tgt + (size_t)b * HW + base);
    const int iters = per_chunk / 4;  // 8192 float4 elements

    float* mybins = &bins[tid * NC];
    int* mycbins = &cbins[tid * NC];

    for (int v = tid; v < iters; v += TPB) {
        float4 z = segv[v];
        int4 t = tgtv[v];
        mybins[t.x] += z.x;
        mybins[t.y] += z.y;
        mybins[t.z] += z.z;
        mybins[t.w] += z.w;
        if (do_count) {
            mycbins[t.x] += 1;
            mycbins[t.y] += 1;
            mycbins[t.z] += 1;
            mycbins[t.w] += 1;
        }
    }
    __syncthreads();

    // Tree-reduce the per-thread bins across the block.
    for (int s = TPB / 2; s > 0; s >>= 1) {
        if (tid < s) {
            #pragma unroll
            for (int k = 0; k < NC; ++k)
                bins[tid * NC + k] += bins[(tid + s) * NC + k];
            if (do_count) {
                #pragma unroll
                for (int k = 0; k < NC; ++k)
                    cbins[tid * NC + k] += cbins[(tid + s) * NC + k];
            }
        }
        __syncthreads();
    }

    if (tid < NC) {
        atomicAdd(&S[((size_t)b * NC + ci) * NC + tid], bins[tid]);
        if (do_count) atomicAdd(&counts[b * NC + tid], cbins[tid]);
    }
}

__global__ __launch_bounds__(256) void finalize_kernel(const float* __restrict__ S,
                                                       const int* __restrict__ counts,
                                                       float* __restrict__ out) {
    const int tid = threadIdx.x;
    const float eps = 2.220446049250313e-16f;  // np.spacing(1)
    float local = 0.0f;

    for (int idx = tid; idx < NB * NC * NC; idx += 256) {
        int b = idx / (NC * NC);
        int r = idx % (NC * NC);
        int i = r / NC;
        int k = r % NC;
        float cnt_i = (float)counts[b * NC + i];
        float cnt_k = (float)counts[b * NC + k];
        float alpha = (cnt_i > 0.0f) ? S[((size_t)b * NC + i) * NC + i] / cnt_i : 0.0f;
        float beta = (cnt_k > 0.0f) ? 1.0f - S[((size_t)b * NC + i) * NC + k] / cnt_k : 0.0f;
        local += logf(0.5f * (alpha + beta + eps));
    }

    // Wave64 shuffle reduction, then cross-wave via LDS.
    #pragma unroll
    for (int off = 32; off > 0; off >>= 1) local += __shfl_down(local, off);

    __shared__ float wsum[4];
    const int wave = tid >> 6;
    const int lane = tid & 63;
    if (lane == 0) wsum[wave] = local;
    __syncthreads();
    if (tid == 0) {
        float total = wsum[0] + wsum[1] + wsum[2] + wsum[3];
        out[0] = -0.5f * total / (float)NB;
    }
}

extern "C" void kernel_launch(void* const* d_in, const int* in_sizes, int n_in,
                              void* d_out, int out_size, void* d_ws, size_t ws_size,
                              hipStream_t stream) {
    const float* seg = (const float*)d_in[0];
    const int* tgt = (const int*)d_in[1];

    float* S = (float*)d_ws;
    int* counts = (int*)((char*)d_ws + (size_t)NB * NC * NC * sizeof(float));
    const size_t ws_used = (size_t)NB * NC * NC * sizeof(float) + (size_t)NB * NC * sizeof(int);

    hipMemsetAsync(d_ws, 0, ws_used, stream);

    dim3 grid(CHUNKS, NC, NB);
    accum_kernel<<<grid, TPB, 0, stream>>>(seg, tgt, S, counts);
    finalize_kernel<<<1, 256, 0, stream>>>(S, counts, (float*)d_out);
}

// Round 2
// 247.169 us; speedup vs baseline: 1.0477x; 1.0477x over previous
//
#include <hip/hip_runtime.h>
#include <math.h>

#define NC 19
#define NB 8
#define HW (512 * 512)
#define CHUNKS 8
#define TPB 256
#define STRIDE 39  // 2*NC + 1 pad: odd stride -> thread bases spread over all 32 banks
#define FT 1024

// Workspace layout (no zero-init needed; every slot written unconditionally):
//   S_part[NB][NC][CHUNKS][NC]  float   (8*19*8*19 = 23104)
//   C_part[NB][CHUNKS][NC]      float   (8*8*19   = 1216)

__global__ __launch_bounds__(TPB) void accum_kernel(const float* __restrict__ seg,
                                                    const int* __restrict__ tgt,
                                                    float* __restrict__ S_part,
                                                    float* __restrict__ C_part) {
    // Per-thread private bins: 2 rows of NC floats. Two rows -> two independent
    // LDS read-modify-write chains per float4 (halves the lgkmcnt serialization).
    __shared__ float bins[TPB * STRIDE];

    const int tid = threadIdx.x;
    const int chunk = blockIdx.x;  // pixel chunk
    const int ci = blockIdx.y;     // channel i
    const int b = blockIdx.z;      // batch
    const bool do_count = (ci == 0);

    float* p0 = &bins[tid * STRIDE];
    float* p1 = p0 + NC;

    #pragma unroll
    for (int k = 0; k < STRIDE; ++k) p0[k] = 0.0f;
    // No barrier needed: rows are thread-private until the reduction.

    const int per_chunk = HW / CHUNKS;  // 32768 pixels
    const size_t pix_base = (size_t)chunk * per_chunk;
    const float4* __restrict__ segv =
        (const float4*)(seg + ((size_t)(b * NC + ci)) * HW + pix_base);
    const int4* __restrict__ tgtv = (const int4*)(tgt + (size_t)b * HW + pix_base);
    const int iters = per_chunk / 4;  // 8192 float4 elements

    if (!do_count) {
        for (int v = tid; v < iters; v += TPB) {
            float4 z = segv[v];
            int4 t = tgtv[v];
            p0[t.x] += z.x;
            p1[t.y] += z.y;   // independent chain
            p0[t.z] += z.z;
            p1[t.w] += z.w;
        }
    } else {
        // ci==0 blocks also produce the class counts (float counting is exact
        // up to 2^24; max count here is 32768). row0 = sums, row1 = counts.
        for (int v = tid; v < iters; v += TPB) {
            float4 z = segv[v];
            int4 t = tgtv[v];
            p0[t.x] += z.x;
            p0[t.y] += z.y;
            p0[t.z] += z.z;
            p0[t.w] += z.w;
            p1[t.x] += 1.0f;
            p1[t.y] += 1.0f;
            p1[t.z] += 1.0f;
            p1[t.w] += 1.0f;
        }
    }
    __syncthreads();

    // Stage 1: fold 256 rows -> 32 rows, flat-parallel over (row, col).
    // Each (r2,c) element owned by exactly one thread; in-place safe.
    for (int e = tid; e < 32 * 2 * NC; e += TPB) {  // 1216 elements
        int r2 = e & 31;
        int c = e >> 5;  // 0..37
        float acc = 0.0f;
        #pragma unroll
        for (int j = 0; j < TPB / 32; ++j) acc += bins[(r2 + 32 * j) * STRIDE + c];
        bins[r2 * STRIDE + c] = acc;
    }
    __syncthreads();

    // Stage 2: 38 lanes (one wave) sum the 32 remaining rows per column, then
    // combine row0/row1 with a shuffle and write partials to unique ws slots.
    if (tid < 2 * NC) {
        float acc = 0.0f;
        #pragma unroll
        for (int r2 = 0; r2 < 32; ++r2) acc += bins[r2 * STRIDE + tid];
        float other = __shfl_down(acc, NC);  // lanes 0..18 receive row1's column sum
        if (tid < NC) {
            const size_t sidx = (((size_t)(b * NC + ci)) * CHUNKS + chunk) * NC + tid;
            if (do_count) {
                S_part[sidx] = acc;  // row0 = sum of z
                C_part[((size_t)b * CHUNKS + chunk) * NC + tid] = other;  // row1 = counts
            } else {
                S_part[sidx] = acc + other;
            }
        }
    }
}

__global__ __launch_bounds__(FT) void finalize_kernel(const float* __restrict__ S_part,
                                                      const float* __restrict__ C_part,
                                                      float* __restrict__ out) {
    __shared__ float Ssum[NB * NC * NC];  // 2888 floats
    __shared__ float Csum[NB * NC];       // 152 floats
    __shared__ float wsum[FT / 64];

    const int tid = threadIdx.x;

    // Phase A: coalesced reduction of chunk partials into LDS.
    for (int e = tid; e < NB * NC * NC; e += FT) {
        int bi = e / NC;       // b*NC + i
        int k = e - bi * NC;
        float a = 0.0f;
        #pragma unroll
        for (int ch = 0; ch < CHUNKS; ++ch)
            a += S_part[((size_t)bi * CHUNKS + ch) * NC + k];
        Ssum[e] = a;
    }
    for (int e = tid; e < NB * NC; e += FT) {
        int bb = e / NC;
        int k = e - bb * NC;
        float a = 0.0f;
        #pragma unroll
        for (int ch = 0; ch < CHUNKS; ++ch)
            a += C_part[((size_t)bb * CHUNKS + ch) * NC + k];
        Csum[e] = a;
    }
    __syncthreads();

    // Phase B: 2888 log terms from LDS.
    const float eps = 2.220446049250313e-16f;  // np.spacing(1)
    float local = 0.0f;
    for (int idx = tid; idx < NB * NC * NC; idx += FT) {
        int b = idx / (NC * NC);
        int r = idx - b * NC * NC;
        int i = r / NC;
        int k = r - i * NC;
        float cnt_i = Csum[b * NC + i];
        float cnt_k = Csum[b * NC + k];
        float alpha = (cnt_i > 0.0f) ? Ssum[(b * NC + i) * NC + i] / cnt_i : 0.0f;
        float beta = (cnt_k > 0.0f) ? 1.0f - Ssum[(b * NC + i) * NC + k] / cnt_k : 0.0f;
        local += logf(0.5f * (alpha + beta + eps));
    }

    #pragma unroll
    for (int off = 32; off > 0; off >>= 1) local += __shfl_down(local, off);
    if ((tid & 63) == 0) wsum[tid >> 6] = local;
    __syncthreads();
    if (tid == 0) {
        float t = 0.0f;
        #pragma unroll
        for (int w = 0; w < FT / 64; ++w) t += wsum[w];
        out[0] = -0.5f * t / (float)NB;
    }
}

extern "C" void kernel_launch(void* const* d_in, const int* in_sizes, int n_in,
                              void* d_out, int out_size, void* d_ws, size_t ws_size,
                              hipStream_t stream) {
    const float* seg = (const float*)d_in[0];
    const int* tgt = (const int*)d_in[1];

    float* S_part = (float*)d_ws;
    float* C_part = S_part + (size_t)NB * NC * CHUNKS * NC;

    dim3 grid(CHUNKS, NC, NB);
    accum_kernel<<<grid, TPB, 0, stream>>>(seg, tgt, S_part, C_part);
    finalize_kernel<<<1, FT, 0, stream>>>(S_part, C_part, (float*)d_out);
}

// Round 3
// 232.573 us; speedup vs baseline: 1.1135x; 1.0628x over previous
//
#include <hip/hip_runtime.h>
#include <math.h>

#define NC 19
#define NB 8
#define HW (512 * 512)
#define CHUNKS 16
#define GROUPS 10  // 9 channel-pairs + 1 singleton (ch 18 + counts)
#define TPB 256
#define STRIDE 39  // 2*NC + 1 pad: odd stride -> bases spread over all 32 banks
#define FT 1024

typedef float v4f __attribute__((ext_vector_type(4)));
typedef int v4i __attribute__((ext_vector_type(4)));

// Workspace layout (no zero-init needed; every slot written unconditionally):
//   S_part[NB][NC][CHUNKS][NC]  float   (8*19*16*19 = 46208)
//   C_part[NB][CHUNKS][NC]      float   (8*16*19   = 2432)

__global__ __launch_bounds__(TPB) void accum_kernel(const float* __restrict__ seg,
                                                    const int* __restrict__ tgt,
                                                    float* __restrict__ S_part,
                                                    float* __restrict__ C_part) {
    __shared__ float bins[TPB * STRIDE];

    const int tid = threadIdx.x;
    const int chunk = blockIdx.x;
    const int g = blockIdx.y;
    const int b = blockIdx.z;
    const bool single = (g == GROUPS - 1);  // channel 18 alone, also does counts
    const int c0 = 2 * g;
    const int c1 = 2 * g + 1;  // unused when single

    float* p0 = &bins[tid * STRIDE];
    float* p1 = p0 + NC;
    #pragma unroll
    for (int k = 0; k < STRIDE; ++k) p0[k] = 0.0f;
    // rows are thread-private until the reduction: no barrier needed here.

    const int per_chunk = HW / CHUNKS;  // 16384 pixels
    const size_t pix = (size_t)chunk * per_chunk;
    const v4f* __restrict__ segA = (const v4f*)(seg + ((size_t)(b * NC + c0)) * HW + pix);
    const v4f* __restrict__ segB = (const v4f*)(seg + ((size_t)(b * NC + c1)) * HW + pix);
    const v4i* __restrict__ tgtv = (const v4i*)(tgt + (size_t)b * HW + pix);
    const int iters = per_chunk / 4 / TPB;  // 16

    // Software pipeline: keep next iteration's loads in flight across the LDS RMWs.
    int v = tid;
    v4f za = __builtin_nontemporal_load(segA + v);  // seg is read-once: don't thrash L2/L3
    v4i t = tgtv[v];                                // tgt is reused by other groups: cacheable
    v4f zb;
    if (!single) zb = __builtin_nontemporal_load(segB + v);

    for (int i = 0; i < iters; ++i) {
        const int vn = v + TPB;
        v4f za_n, zb_n;
        v4i tn;
        if (i + 1 < iters) {
            za_n = __builtin_nontemporal_load(segA + vn);
            tn = tgtv[vn];
            if (!single) zb_n = __builtin_nontemporal_load(segB + vn);
        }
        if (!single) {
            // Two independent LDS RMW chains (one per channel), same target reused.
            p0[t.x] += za.x;  p1[t.x] += zb.x;
            p0[t.y] += za.y;  p1[t.y] += zb.y;
            p0[t.z] += za.z;  p1[t.z] += zb.z;
            p0[t.w] += za.w;  p1[t.w] += zb.w;
        } else {
            // row0 = ch18 sums; row1 = counts (exact in float up to 2^24).
            p0[t.x] += za.x;  p1[t.x] += 1.0f;
            p0[t.y] += za.y;  p1[t.y] += 1.0f;
            p0[t.z] += za.z;  p1[t.z] += 1.0f;
            p0[t.w] += za.w;  p1[t.w] += 1.0f;
        }
        za = za_n; zb = zb_n; t = tn; v = vn;
    }
    __syncthreads();

    // Stage 1: fold 256 rows -> 32 rows, flat-parallel over (row, col).
    for (int e = tid; e < 32 * 2 * NC; e += TPB) {  // 1216 elements
        int r2 = e & 31;
        int c = e >> 5;  // 0..37
        float acc = 0.0f;
        #pragma unroll
        for (int j = 0; j < TPB / 32; ++j) acc += bins[(r2 + 32 * j) * STRIDE + c];
        bins[r2 * STRIDE + c] = acc;
    }
    __syncthreads();

    // Stage 2: 38 lanes (wave 0) sum the 32 remaining rows per column and write
    // partials to unique ws slots. Row0 -> channel c0; row1 -> c1 or counts.
    if (tid < 2 * NC) {
        float acc = 0.0f;
        #pragma unroll
        for (int r2 = 0; r2 < 32; ++r2) acc += bins[r2 * STRIDE + tid];
        if (tid < NC) {
            S_part[(((size_t)(b * NC + c0)) * CHUNKS + chunk) * NC + tid] = acc;
        } else {
            const int k = tid - NC;
            if (!single)
                S_part[(((size_t)(b * NC + c1)) * CHUNKS + chunk) * NC + k] = acc;
            else
                C_part[((size_t)b * CHUNKS + chunk) * NC + k] = acc;
        }
    }
}

__global__ __launch_bounds__(FT) void finalize_kernel(const float* __restrict__ S_part,
                                                      const float* __restrict__ C_part,
                                                      float* __restrict__ out) {
    __shared__ float Ssum[NB * NC * NC];  // 2888 floats
    __shared__ float Csum[NB * NC];       // 152 floats
    __shared__ float wsum[FT / 64];

    const int tid = threadIdx.x;

    // Phase A: coalesced reduction of chunk partials into LDS.
    for (int e = tid; e < NB * NC * NC; e += FT) {
        int bi = e / NC;  // b*NC + i
        int k = e - bi * NC;
        float a = 0.0f;
        #pragma unroll
        for (int ch = 0; ch < CHUNKS; ++ch)
            a += S_part[((size_t)bi * CHUNKS + ch) * NC + k];
        Ssum[e] = a;
    }
    for (int e = tid; e < NB * NC; e += FT) {
        int bb = e / NC;
        int k = e - bb * NC;
        float a = 0.0f;
        #pragma unroll
        for (int ch = 0; ch < CHUNKS; ++ch)
            a += C_part[((size_t)bb * CHUNKS + ch) * NC + k];
        Csum[e] = a;
    }
    __syncthreads();

    // Phase B: 2888 log terms from LDS.
    const float eps = 2.220446049250313e-16f;  // np.spacing(1)
    float local = 0.0f;
    for (int idx = tid; idx < NB * NC * NC; idx += FT) {
        int b = idx / (NC * NC);
        int r = idx - b * NC * NC;
        int i = r / NC;
        int k = r - i * NC;
        float cnt_i = Csum[b * NC + i];
        float cnt_k = Csum[b * NC + k];
        float alpha = (cnt_i > 0.0f) ? Ssum[(b * NC + i) * NC + i] / cnt_i : 0.0f;
        float beta = (cnt_k > 0.0f) ? 1.0f - Ssum[(b * NC + i) * NC + k] / cnt_k : 0.0f;
        local += logf(0.5f * (alpha + beta + eps));
    }

    #pragma unroll
    for (int off = 32; off > 0; off >>= 1) local += __shfl_down(local, off);
    if ((tid & 63) == 0) wsum[tid >> 6] = local;
    __syncthreads();
    if (tid == 0) {
        float t = 0.0f;
        #pragma unroll
        for (int w = 0; w < FT / 64; ++w) t += wsum[w];
        out[0] = -0.5f * t / (float)NB;
    }
}

extern "C" void kernel_launch(void* const* d_in, const int* in_sizes, int n_in,
                              void* d_out, int out_size, void* d_ws, size_t ws_size,
                              hipStream_t stream) {
    const float* seg = (const float*)d_in[0];
    const int* tgt = (const int*)d_in[1];

    float* S_part = (float*)d_ws;
    float* C_part = S_part + (size_t)NB * NC * CHUNKS * NC;

    dim3 grid(CHUNKS, GROUPS, NB);
    accum_kernel<<<grid, TPB, 0, stream>>>(seg, tgt, S_part, C_part);
    finalize_kernel<<<1, FT, 0, stream>>>(S_part, C_part, (float*)d_out);
}